// Round 1
// baseline (2844.002 us; speedup 1.0000x reference)
//
#include <hip/hip_runtime.h>

namespace {
constexpr int   NGRID  = 512;
constexpr int   NCELL  = NGRID * NGRID;
constexpr float DX     = 1.0f / (float)NGRID;
constexpr float INV_DX = (float)NGRID;
constexpr float DT     = 1e-4f;
constexpr float P_VOL  = (DX * 0.5f) * (DX * 0.5f);
constexpr float P_MASS = P_VOL * 1.0f;   // p_rho = 1
constexpr float GRAV   = 10.0f;
}

// ---------------- P2G: particle -> grid scatter + F/material/Jp outputs ----
__global__ __launch_bounds__(256) void mpm_p2g(
    const float2* __restrict__ x,
    const float2* __restrict__ v,
    const float4* __restrict__ C,
    const float4* __restrict__ F,
    const int*    __restrict__ material,
    const float*  __restrict__ Jp,
    const float*  __restrict__ Ep,
    const float*  __restrict__ nup,
    float* __restrict__ gvx,
    float* __restrict__ gvy,
    float* __restrict__ gm,
    float4* __restrict__ outF,
    float*  __restrict__ outMat,
    float*  __restrict__ outJp,
    int n)
{
    int p = blockIdx.x * blockDim.x + threadIdx.x;
    if (p >= n) return;

    const float E  = Ep[0];
    const float nu = nup[0];
    const float mu0 = E / (2.0f * (1.0f + nu));
    const float la0 = E * nu / ((1.0f + nu) * (1.0f - 2.0f * nu));

    const float2 xp = x[p];
    const float2 vp = v[p];
    const float4 c4 = C[p];
    const float4 f4 = F[p];
    const float  jp = Jp[p];

    // base cell & fractional position
    const float xs = xp.x * INV_DX, ys = xp.y * INV_DX;
    const int bi = (int)(xs - 0.5f);
    const int bj = (int)(ys - 0.5f);
    const float fxx = xs - (float)bi;
    const float fxy = ys - (float)bj;

    // quadratic B-spline weights
    float wx[3], wy[3];
    { float t0 = 1.5f - fxx, t1 = fxx - 1.0f, t2 = fxx - 0.5f;
      wx[0] = 0.5f * t0 * t0; wx[1] = 0.75f - t1 * t1; wx[2] = 0.5f * t2 * t2; }
    { float t0 = 1.5f - fxy, t1 = fxy - 1.0f, t2 = fxy - 0.5f;
      wy[0] = 0.5f * t0 * t0; wy[1] = 0.75f - t1 * t1; wy[2] = 0.5f * t2 * t2; }

    // F <- F + dt * C @ F
    const float F00 = f4.x + DT * (c4.x * f4.x + c4.y * f4.z);
    const float F01 = f4.y + DT * (c4.x * f4.y + c4.y * f4.w);
    const float F10 = f4.z + DT * (c4.z * f4.x + c4.w * f4.z);
    const float F11 = f4.w + DT * (c4.z * f4.y + c4.w * f4.w);

    const float h  = expf(10.0f * (1.0f - jp));
    const float mu = mu0 * h;
    const float la = la0 * h;

    // closed-form 2x2 polar rotation R = [[c,-s],[s,c]]
    const float a = F00 + F11;
    const float b = F10 - F01;
    const float r = sqrtf(a * a + b * b);
    const float cth = a / r;
    const float sth = b / r;
    const float J = fabsf(F00 * F11 - F01 * F10);

    // PF = (F - R) @ F^T
    const float A00 = F00 - cth, A01 = F01 + sth;
    const float A10 = F10 - sth, A11 = F11 - cth;
    const float PF00 = A00 * F00 + A01 * F01;
    const float PF01 = A00 * F10 + A01 * F11;
    const float PF10 = A10 * F00 + A11 * F01;
    const float PF11 = A10 * F10 + A11 * F11;

    constexpr float SC = -DT * P_VOL * 4.0f * INV_DX * INV_DX;
    const float diag = la * J * (J - 1.0f);
    const float twomu = 2.0f * mu;
    const float S00 = SC * (twomu * PF00 + diag);
    const float S01 = SC * (twomu * PF01);
    const float S10 = SC * (twomu * PF10);
    const float S11 = SC * (twomu * PF11 + diag);

    // affine = stress + p_mass * C
    const float Af00 = S00 + P_MASS * c4.x;
    const float Af01 = S01 + P_MASS * c4.y;
    const float Af10 = S10 + P_MASS * c4.z;
    const float Af11 = S11 + P_MASS * c4.w;

    const float mvx = P_MASS * vp.x;
    const float mvy = P_MASS * vp.y;

    #pragma unroll
    for (int i = 0; i < 3; ++i) {
        #pragma unroll
        for (int j = 0; j < 3; ++j) {
            const float wgt = wx[i] * wy[j];
            const float dpx = ((float)i - fxx) * DX;
            const float dpy = ((float)j - fxy) * DX;
            const float cx = wgt * (mvx + Af00 * dpx + Af01 * dpy);
            const float cy = wgt * (mvy + Af10 * dpx + Af11 * dpy);
            const int idx = (bi + i) * NGRID + (bj + j);
            atomicAdd(&gvx[idx], cx);
            atomicAdd(&gvy[idx], cy);
            atomicAdd(&gm[idx], wgt * P_MASS);
        }
    }

    // passthrough outputs
    outF[p] = make_float4(F00, F01, F10, F11);
    outMat[p] = (float)material[p];
    outJp[p]  = jp;
}

// ---------------- grid update: momentum->velocity, gravity, BCs ------------
__global__ __launch_bounds__(256) void mpm_grid(
    float* __restrict__ gvx,
    float* __restrict__ gvy,
    const float* __restrict__ gm)
{
    int idx = blockIdx.x * blockDim.x + threadIdx.x;
    if (idx >= NCELL) return;
    const int i = idx >> 9;        // NGRID = 512
    const int j = idx & (NGRID - 1);

    float m  = gm[idx];
    float vx = gvx[idx];
    float vy = gvy[idx];
    if (m > 0.0f) {
        float inv = 1.0f / fmaxf(m, 1e-30f);
        vx *= inv;
        vy *= inv;
    }
    vy -= DT * GRAV;
    if (i < 3)          vx = fmaxf(vx, 0.0f);
    if (i >= NGRID - 2) vx = fminf(vx, 0.0f);
    if (j < 3)          vy = fmaxf(vy, 0.0f);
    if (j >= NGRID - 2) vy = fminf(vy, 0.0f);
    gvx[idx] = vx;
    gvy[idx] = vy;
}

// ---------------- G2P: grid -> particle gather, x/v/C outputs --------------
__global__ __launch_bounds__(256) void mpm_g2p(
    const float2* __restrict__ x,
    const float* __restrict__ gvx,
    const float* __restrict__ gvy,
    float2* __restrict__ outX,
    float2* __restrict__ outV,
    float4* __restrict__ outC,
    int n)
{
    int p = blockIdx.x * blockDim.x + threadIdx.x;
    if (p >= n) return;

    const float2 xp = x[p];
    const float xs = xp.x * INV_DX, ys = xp.y * INV_DX;
    const int bi = (int)(xs - 0.5f);
    const int bj = (int)(ys - 0.5f);
    const float fxx = xs - (float)bi;
    const float fxy = ys - (float)bj;

    float wx[3], wy[3];
    { float t0 = 1.5f - fxx, t1 = fxx - 1.0f, t2 = fxx - 0.5f;
      wx[0] = 0.5f * t0 * t0; wx[1] = 0.75f - t1 * t1; wx[2] = 0.5f * t2 * t2; }
    { float t0 = 1.5f - fxy, t1 = fxy - 1.0f, t2 = fxy - 0.5f;
      wy[0] = 0.5f * t0 * t0; wy[1] = 0.75f - t1 * t1; wy[2] = 0.5f * t2 * t2; }

    float nvx = 0.0f, nvy = 0.0f;
    float C00 = 0.0f, C01 = 0.0f, C10 = 0.0f, C11 = 0.0f;
    constexpr float K4 = 4.0f * INV_DX * INV_DX;

    #pragma unroll
    for (int i = 0; i < 3; ++i) {
        #pragma unroll
        for (int j = 0; j < 3; ++j) {
            const float wgt = wx[i] * wy[j];
            const float dpx = ((float)i - fxx) * DX;
            const float dpy = ((float)j - fxy) * DX;
            const int idx = (bi + i) * NGRID + (bj + j);
            const float gx = gvx[idx];
            const float gy = gvy[idx];
            nvx += wgt * gx;
            nvy += wgt * gy;
            const float kw = K4 * wgt;
            C00 += kw * gx * dpx;
            C01 += kw * gx * dpy;
            C10 += kw * gy * dpx;
            C11 += kw * gy * dpy;
        }
    }

    outX[p] = make_float2(xp.x + DT * nvx, xp.y + DT * nvy);
    outV[p] = make_float2(nvx, nvy);
    outC[p] = make_float4(C00, C01, C10, C11);
}

extern "C" void kernel_launch(void* const* d_in, const int* in_sizes, int n_in,
                              void* d_out, int out_size, void* d_ws, size_t ws_size,
                              hipStream_t stream) {
    const int n = in_sizes[0] / 2;   // N_PART

    const float2* x   = (const float2*)d_in[0];
    const float2* v   = (const float2*)d_in[1];
    const float4* C   = (const float4*)d_in[2];
    const float4* F   = (const float4*)d_in[3];
    const int*    mat = (const int*)d_in[4];
    const float*  Jp  = (const float*)d_in[5];
    const float*  Ep  = (const float*)d_in[6];
    const float*  nup = (const float*)d_in[7];

    float* out = (float*)d_out;
    float2* o_x = (float2*)(out);              // 2n floats
    float2* o_v = (float2*)(out + 2 * (size_t)n);
    float4* o_C = (float4*)(out + 4 * (size_t)n);
    float4* o_F = (float4*)(out + 8 * (size_t)n);
    float*  o_m = out + 12 * (size_t)n;
    float*  o_J = out + 13 * (size_t)n;

    // grid scratch in workspace: gvx | gvy | gm
    float* gvx = (float*)d_ws;
    float* gvy = gvx + NCELL;
    float* gm  = gvy + NCELL;

    hipMemsetAsync(d_ws, 0, (size_t)NCELL * 3 * sizeof(float), stream);

    const int BLK = 256;
    const int pgrid = (n + BLK - 1) / BLK;

    mpm_p2g<<<pgrid, BLK, 0, stream>>>(x, v, C, F, mat, Jp, Ep, nup,
                                       gvx, gvy, gm, o_F, o_m, o_J, n);
    mpm_grid<<<(NCELL + BLK - 1) / BLK, BLK, 0, stream>>>(gvx, gvy, gm);
    mpm_g2p<<<pgrid, BLK, 0, stream>>>(x, gvx, gvy, o_x, o_v, o_C, n);
}